// Round 8
// baseline (157.495 us; speedup 1.0000x reference)
//
#include <hip/hip_runtime.h>
#include <hip/hip_bf16.h>
#include <stdint.h>

using bf16   = __bf16;
using bf16x4 = __attribute__((ext_vector_type(4))) __bf16;
using bf16x8 = __attribute__((ext_vector_type(8))) __bf16;
using f32x4  = __attribute__((ext_vector_type(4))) float;

// geometry (fixed by the problem)
static constexpr int BATCH = 4, SEQ = 2048, DIM = 512, HEADS = 8, DK = 64;
static constexpr int M    = BATCH * SEQ;   // 8192 rows of x
static constexpr int NQKV = 3 * DIM;       // 1536

// ---------------------------------------------------------------------------
// Kernel 1 (tiny): W [512][1536] fp32 -> Wt [1536][512] bf16.
// ---------------------------------------------------------------------------
__global__ __launch_bounds__(256) void k_prep(const float* __restrict__ w,
                                              bf16* __restrict__ wt)
{
    const int bid = blockIdx.x;                             // 768 blocks
    const int t   = threadIdx.x;
    const int rt = bid / 48, ct = bid - rt * 48;            // k-tile, n-tile
    __shared__ float tile[32][33];
    const int r = t >> 5, c = t & 31;
    #pragma unroll
    for (int i = 0; i < 4; ++i)
        tile[r + i * 8][c] = w[(rt * 32 + r + i * 8) * NQKV + ct * 32 + c];
    __syncthreads();
    #pragma unroll
    for (int i = 0; i < 4; ++i)
        wt[(ct * 32 + r + i * 8) * DIM + rt * 32 + c] = (bf16)tile[c][r + i * 8];
}

// ---------------------------------------------------------------------------
// Kernel 2: per (m-tile 128, head h): GEMM cols {q_h|k_h|v_h} (128x192,
// 6 waves of 64x64).  NO LDS / NO barriers in the K-loop: each wave loads its
// A fragments straight from fp32 x (cvt in-reg) and B fragments straight from
// bf16 Wt.  Reuse comes from L1/L2 (Wt per head = 192KB, shared by 64 blocks;
// x rows shared by the block's 3 sections).  Waves run fully decoupled ->
// latency hidden by ILP (24 independent loads/iter) + TLP (12 waves/CU).
// Fused epilogue (identical to round 6): q-waves LN->transpose->qn; k-waves
// LN->kst LDS; v-waves cast->vst LDS; barrier; v-waves MFMA the 128-row
// partial S[d'][d], cross-wave LDS reduce, plain store to Sp.
// ---------------------------------------------------------------------------
__global__ __launch_bounds__(384, 3) void k_gemm(const float* __restrict__ x,
                                                 const bf16* __restrict__ Wt,
                                                 const float* __restrict__ gq,
                                                 const float* __restrict__ bq,
                                                 const float* __restrict__ gk,
                                                 const float* __restrict__ bk,
                                                 bf16* __restrict__ qn,
                                                 float* __restrict__ Sp)
{
    __shared__ struct {
        bf16 q[2][64][72]; bf16 kst[64 * 128]; bf16 vst[64 * 128];
    } e;                                          // 50 KB (epilogue only)

    const int t    = threadIdx.x;
    const int lane = t & 63, wave = t >> 6;      // 6 waves
    const int wm   = wave & 1, ws = wave >> 1;   // row-half, section (q/k/v)
    const int orig = blockIdx.x;                 // 512 blocks, 512 % 8 == 0
    const int wg   = (orig & 7) * 64 + (orig >> 3);  // XCD-contiguous
    const int mt   = wg >> 3, h = wg & 7;
    const int m0   = mt * 128;

    const int l15 = lane & 15, l4 = lane >> 4;

    f32x4 acc[4][4] = {};

    const float* xbase = x + (long)(m0 + wm * 64 + l15) * 512;
    const bf16*  wbase = Wt + (long)(ws * 512 + h * 64 + l15) * 512;

    for (int k0 = 0; k0 < 512; k0 += 64) {
        bf16x8 bfv[2][4];
        bf16x8 af[2][4];
        #pragma unroll
        for (int kh = 0; kh < 2; ++kh) {
            const int col = k0 + (kh * 4 + l4) * 8;
            #pragma unroll
            for (int nf = 0; nf < 4; ++nf)
                bfv[kh][nf] = *(const bf16x8*)(wbase + (long)(nf * 16) * 512 + col);
            #pragma unroll
            for (int mf = 0; mf < 4; ++mf) {
                const float* ap = xbase + (long)(mf * 16) * 512 + col;
                float4 lo = *(const float4*)(ap);
                float4 hi = *(const float4*)(ap + 4);
                bf16x8 f;
                f[0] = (bf16)lo.x; f[1] = (bf16)lo.y; f[2] = (bf16)lo.z; f[3] = (bf16)lo.w;
                f[4] = (bf16)hi.x; f[5] = (bf16)hi.y; f[6] = (bf16)hi.z; f[7] = (bf16)hi.w;
                af[kh][mf] = f;
            }
        }
        #pragma unroll
        for (int kh = 0; kh < 2; ++kh)
            #pragma unroll
            for (int mf = 0; mf < 4; ++mf)
                #pragma unroll
                for (int nf = 0; nf < 4; ++nf)
                    acc[mf][nf] = __builtin_amdgcn_mfma_f32_16x16x32_bf16(
                        af[kh][mf], bfv[kh][nf], acc[mf][nf], 0, 0, 0);
    }

    // ---------------- fused epilogue (round-6 verified code) ----------------
    const int b  = m0 >> 11;
    const int bh = b * 8 + h;
    const int nwbase = (m0 & 2047) + wm * 64;    // seq offset of wave's 64 rows

    if (ws < 2) {
        // LayerNorm over d=64 (4 nf frags x 16 l15 lanes), stats from fp32 acc
        const float* gp = (ws == 0 ? gq : gk) + h * 64;
        const float* bp = (ws == 0 ? bq : bk) + h * 64;
        float gv[4], bv[4];
        #pragma unroll
        for (int nf = 0; nf < 4; ++nf) {
            gv[nf] = gp[nf * 16 + l15];
            bv[nf] = bp[nf * 16 + l15];
        }
        #pragma unroll
        for (int mf = 0; mf < 4; ++mf) {
            float mu[4], rs[4];
            #pragma unroll
            for (int r = 0; r < 4; ++r) {
                float s = 0.f, s2 = 0.f;
                #pragma unroll
                for (int nf = 0; nf < 4; ++nf) {
                    const float xv = acc[mf][nf][r];
                    s += xv; s2 += xv * xv;
                }
                s  += __shfl_xor(s, 1);  s  += __shfl_xor(s, 2);
                s  += __shfl_xor(s, 4);  s  += __shfl_xor(s, 8);
                s2 += __shfl_xor(s2, 1); s2 += __shfl_xor(s2, 2);
                s2 += __shfl_xor(s2, 4); s2 += __shfl_xor(s2, 8);
                mu[r] = s * (1.f / 64.f);
                rs[r] = rsqrtf(s2 * (1.f / 64.f) - mu[r] * mu[r] + 1e-5f);
            }
            #pragma unroll
            for (int nf = 0; nf < 4; ++nf) {
                bf16x4 pk;
                #pragma unroll
                for (int r = 0; r < 4; ++r)
                    pk[r] = (bf16)((acc[mf][nf][r] - mu[r]) * rs[r] * gv[nf] + bv[nf]);
                if (ws == 0) {
                    *(bf16x4*)(&e.q[wm][nf * 16 + l15][mf * 16 + l4 * 4]) = pk;
                } else {
                    const int d = nf * 16 + l15;
                    const int c = wm * 8 + mf * 2 + (l4 >> 1);   // n-chunk 0..15
                    *(bf16x4*)(e.kst + d * 128 + ((c ^ (d & 7)) * 8) + (l4 & 1) * 4) = pk;
                }
            }
        }
    } else {
        // v: plain cast into vst[d'][128n], same swizzle
        #pragma unroll
        for (int mf = 0; mf < 4; ++mf)
            #pragma unroll
            for (int nf = 0; nf < 4; ++nf) {
                bf16x4 pk;
                #pragma unroll
                for (int r = 0; r < 4; ++r) pk[r] = (bf16)acc[mf][nf][r];
                const int d = nf * 16 + l15;
                const int c = wm * 8 + mf * 2 + (l4 >> 1);
                *(bf16x4*)(e.vst + d * 128 + ((c ^ (d & 7)) * 8) + (l4 & 1) * 4) = pk;
            }
    }

    if (ws == 0) {
        // wave-local 4x4 transpose qep[d][n] -> qn[bh][n][d]
        bf16* dst = qn + ((long)bh * SEQ + nwbase) * 64;
        const int nq = lane & 15, dq2 = lane >> 4;
        #pragma unroll
        for (int j = 0; j < 4; ++j) {
            const int d0 = (j * 4 + dq2) * 4;
            bf16x4 a0 = *(const bf16x4*)(&e.q[wm][d0 + 0][nq * 4]);
            bf16x4 a1 = *(const bf16x4*)(&e.q[wm][d0 + 1][nq * 4]);
            bf16x4 a2 = *(const bf16x4*)(&e.q[wm][d0 + 2][nq * 4]);
            bf16x4 a3 = *(const bf16x4*)(&e.q[wm][d0 + 3][nq * 4]);
            #pragma unroll
            for (int c = 0; c < 4; ++c) {
                bf16x4 o = { a0[c], a1[c], a2[c], a3[c] };
                *(bf16x4*)(dst + (nq * 4 + c) * 64 + d0) = o;
            }
        }
    }

    __syncthreads();   // kst/vst complete for all waves

    if (ws == 2) {
        // partial S[d'][d] over this block's 128 rows; wave wm does ks pair
        f32x4 sac[4][4] = {};
        #pragma unroll
        for (int kk = 0; kk < 2; ++kk) {
            const int ksi = wm * 2 + kk;          // 0..3 (n-chunk of 32)
            const int c   = ksi * 4 + l4;         // 16B chunk 0..15
            bf16x8 av[4], bk8[4];
            #pragma unroll
            for (int i = 0; i < 4; ++i) {
                const int dp = i * 16 + l15;
                av[i] = *(const bf16x8*)(e.vst + dp * 128 + ((c ^ (dp & 7)) * 8));
            }
            #pragma unroll
            for (int j = 0; j < 4; ++j) {
                const int dd = j * 16 + l15;
                bk8[j] = *(const bf16x8*)(e.kst + dd * 128 + ((c ^ (dd & 7)) * 8));
            }
            #pragma unroll
            for (int i = 0; i < 4; ++i)
                #pragma unroll
                for (int j = 0; j < 4; ++j)
                    sac[i][j] = __builtin_amdgcn_mfma_f32_16x16x32_bf16(
                        av[i], bk8[j], sac[i][j], 0, 0, 0);
        }
        // sum the two ws==2 waves' disjoint n-chunks via LDS (q area free)
        float* red = (float*)e.q;                 // 16KB scratch
        if (wm == 0) {
            #pragma unroll
            for (int i = 0; i < 4; ++i)
                #pragma unroll
                for (int j = 0; j < 4; ++j)
                    #pragma unroll
                    for (int r = 0; r < 4; ++r)
                        red[(i * 16 + l4 * 4 + r) * 64 + j * 16 + l15] = sac[i][j][r];
        }
        __builtin_amdgcn_s_barrier();
        if (wm == 1) {
            float* Sb = Sp + (long)(mt * 8 + h) * 4096;
            #pragma unroll
            for (int i = 0; i < 4; ++i)
                #pragma unroll
                for (int j = 0; j < 4; ++j)
                    #pragma unroll
                    for (int r = 0; r < 4; ++r) {
                        const int dp = i * 16 + l4 * 4 + r;
                        const int dd = j * 16 + l15;
                        Sb[dp * 64 + dd] = sac[i][j][r] + red[dp * 64 + dd];
                    }
        }
    }
}

// ---------------------------------------------------------------------------
// Kernel 3 (tiny): reduce Sp (16 m-partials per bh) -> S[bh][64][64].
// 512 blocks x 256 thr; fully coalesced.
// ---------------------------------------------------------------------------
__global__ __launch_bounds__(256) void k_red(const float* __restrict__ Sp,
                                             float* __restrict__ S)
{
    const int bid = blockIdx.x;
    const int bh = bid >> 4, chunk = bid & 15;
    const int b = bh >> 3, h = bh & 7;
    const int e = chunk * 256 + threadIdx.x;
    float s = 0.f;
    #pragma unroll 4
    for (int p = 0; p < 16; ++p)
        s += Sp[((long)((b * 16 + p) * 8 + h)) * 4096 + e];
    S[(long)bh * 4096 + e] = s;
}

// ---------------------------------------------------------------------------
// Kernel 4: out[b][n][h*64+d'] = sum_d qn[bh][n][d] * (S[bh][d'][d] * 2^-14)
// 512 blocks (32 bh x 16 n-tiles of 128), 4 waves x 32 rows -> 8 waves/CU.
// ---------------------------------------------------------------------------
__global__ __launch_bounds__(256) void k_out(const bf16* __restrict__ qn,
                                             const float* __restrict__ S,
                                             float* __restrict__ out)
{
    __shared__ float sS[64 * 68];                // padded [64][68]
    const int bid = blockIdx.x;
    const int bh = bid >> 4, nt16 = bid & 15;
    const int b = bh >> 3, h = bh & 7;
    const int t = threadIdx.x, lane = t & 63, wave = t >> 6;
    const int l15 = lane & 15, l4 = lane >> 4;

    // ---- load S tile (L2-hot, coalesced) into padded LDS ----
    #pragma unroll
    for (int j = 0; j < 4; ++j) {
        const int f  = j * 1024 + t * 4;
        const int dp = f >> 6, dd = f & 63;
        *(f32x4*)(sS + dp * 68 + dd) = *(const f32x4*)(S + (long)bh * 4096 + f);
    }
    __syncthreads();

    // ---- build bf16 B-frags with scale folded in ----
    const float scale = 1.f / 16384.f;           // (64^-0.5)/2048 exactly
    bf16x8 bfr[2][4];
    #pragma unroll
    for (int kh = 0; kh < 2; ++kh)
        #pragma unroll
        for (int cf = 0; cf < 4; ++cf) {
            const float* p = sS + (cf * 16 + l15) * 68 + kh * 32 + l4 * 8;
            float4 lo = *(const float4*)(p);
            float4 hi = *(const float4*)(p + 4);
            bf16x8 f;
            f[0] = (bf16)(lo.x * scale); f[1] = (bf16)(lo.y * scale);
            f[2] = (bf16)(lo.z * scale); f[3] = (bf16)(lo.w * scale);
            f[4] = (bf16)(hi.x * scale); f[5] = (bf16)(hi.y * scale);
            f[6] = (bf16)(hi.z * scale); f[7] = (bf16)(hi.w * scale);
            bfr[kh][cf] = f;
        }

    const bf16* qb = qn + (long)bh * SEQ * 64;
    const int nbase = nt16 * 128 + wave * 32;

    #pragma unroll
    for (int mf = 0; mf < 2; ++mf) {
        bf16x8 a0 = *(const bf16x8*)(qb + (nbase + mf * 16 + l15) * 64 +      l4 * 8);
        bf16x8 a1 = *(const bf16x8*)(qb + (nbase + mf * 16 + l15) * 64 + 32 + l4 * 8);
        f32x4 acc[4] = {};
        #pragma unroll
        for (int cf = 0; cf < 4; ++cf) {
            acc[cf] = __builtin_amdgcn_mfma_f32_16x16x32_bf16(a0, bfr[0][cf], acc[cf], 0, 0, 0);
            acc[cf] = __builtin_amdgcn_mfma_f32_16x16x32_bf16(a1, bfr[1][cf], acc[cf], 0, 0, 0);
        }
        #pragma unroll
        for (int cf = 0; cf < 4; ++cf)
            #pragma unroll
            for (int r = 0; r < 4; ++r) {
                const int n = nbase + mf * 16 + l4 * 4 + r;
                out[((long)b * SEQ + n) * 512 + h * 64 + cf * 16 + l15] = acc[cf][r];
            }
    }
}

// ---------------------------------------------------------------------------
extern "C" void kernel_launch(void* const* d_in, const int* in_sizes, int n_in,
                              void* d_out, int out_size, void* d_ws, size_t ws_size,
                              hipStream_t stream)
{
    const float* x  = (const float*)d_in[0];
    const float* w  = (const float*)d_in[1];
    const float* gq = (const float*)d_in[2];
    const float* bq = (const float*)d_in[3];
    const float* gk = (const float*)d_in[4];
    const float* bk = (const float*)d_in[5];
    float* out = (float*)d_out;

    char* ws = (char*)d_ws;
    // layout (bytes):
    //   wt  bf16 : 0        .. 1572864
    //   qn  bf16 : 1572864  .. 9961472
    //   Sp  fp32 : 9961472  .. 18350080  (64 mt x 8 h x 4096 f32 = 8 MB)
    //   S   fp32 : 18350080 .. 18874368  (32 bh x 4096 f32)
    bf16*  wt = (bf16*)(ws);
    bf16*  qn = (bf16*)(ws + 1572864);
    float* Sp = (float*)(ws + 9961472);
    float* S  = (float*)(ws + 18350080);

    hipLaunchKernelGGL(k_prep, dim3(768), dim3(256), 0, stream, w, wt);
    hipLaunchKernelGGL(k_gemm, dim3(512), dim3(384), 0, stream,
                       x, wt, gq, bq, gk, bk, qn, Sp);
    hipLaunchKernelGGL(k_red,  dim3(512), dim3(256), 0, stream, Sp, S);
    hipLaunchKernelGGL(k_out,  dim3(512), dim3(256), 0, stream, qn, S, out);
}

// Round 9
// 110.653 us; speedup vs baseline: 1.4233x; 1.4233x over previous
//
#include <hip/hip_runtime.h>
#include <hip/hip_bf16.h>
#include <stdint.h>

using bf16   = __bf16;
using bf16x4 = __attribute__((ext_vector_type(4))) __bf16;
using bf16x8 = __attribute__((ext_vector_type(8))) __bf16;
using f32x4  = __attribute__((ext_vector_type(4))) float;

// geometry (fixed by the problem)
static constexpr int BATCH = 4, SEQ = 2048, DIM = 512, HEADS = 8, DK = 64;
static constexpr int M    = BATCH * SEQ;   // 8192 rows of x
static constexpr int NQKV = 3 * DIM;       // 1536

#define GLD16(src, dst)                                                        \
    __builtin_amdgcn_global_load_lds(                                          \
        (const __attribute__((address_space(1))) void*)(src),                  \
        (__attribute__((address_space(3))) void*)(dst), 16, 0, 0)

#define WAITVM(N)  asm volatile("s_waitcnt vmcnt(" #N ")" ::: "memory")
#define WAITLGKM0  asm volatile("s_waitcnt lgkmcnt(0)" ::: "memory")

// ---------------------------------------------------------------------------
// Kernel 1 (tiny): W [512][1536] fp32 -> Wt [1536][512] bf16.
// ---------------------------------------------------------------------------
__global__ __launch_bounds__(256) void k_prep(const float* __restrict__ w,
                                              bf16* __restrict__ wt)
{
    const int bid = blockIdx.x;                             // 768 blocks
    const int t   = threadIdx.x;
    const int rt = bid / 48, ct = bid - rt * 48;            // k-tile, n-tile
    __shared__ float tile[32][33];
    const int r = t >> 5, c = t & 31;
    #pragma unroll
    for (int i = 0; i < 4; ++i)
        tile[r + i * 8][c] = w[(rt * 32 + r + i * 8) * NQKV + ct * 32 + c];
    __syncthreads();
    #pragma unroll
    for (int i = 0; i < 4; ++i)
        wt[(ct * 32 + r + i * 8) * DIM + rt * 32 + c] = (bf16)tile[c][r + i * 8];
}

// ---------------------------------------------------------------------------
// Kernel 2: per (m-tile 256, head h): GEMM cols {q_h|k_h|v_h} (256x192,
// 12 waves of 64x64; wm=wave&3 row-quarter, ws=wave>>2 section).
// 256 blocks = exactly 1/CU (no tail).  Double-buffered LDS (112 KB) with
// 1-deep decoupled prefetch and COUNTED vmcnt:
//   per step t: issue A-loads(t+1) [fp32->reg], issue B-GLD16(t+1);
//   wait vmcnt(nA+nB) [stage t landed, stage t+1 still in flight]; barrier;
//   compute(t); wait vmcnt(nB) [A(t+1) regs arrived]; cvt+ds_write A(t+1);
//   lgkmcnt(0); barrier [buffer-reuse protection].
// Fused epilogue (R6-verified, re-indexed): q LN->transpose->qn; k LN->kst;
// v cast->vst; barrier; v-waves MFMA partial S (4-way LDS reduce) -> Sp.
// ---------------------------------------------------------------------------
__global__ __launch_bounds__(768) void k_gemm(const float* __restrict__ x,
                                              const bf16* __restrict__ Wt,
                                              const float* __restrict__ gq,
                                              const float* __restrict__ bq,
                                              const float* __restrict__ gk,
                                              const float* __restrict__ bk,
                                              bf16* __restrict__ qn,
                                              float* __restrict__ Sp)
{
    __shared__ union {
        struct { bf16 A[2][256 * 64]; bf16 B[2][192 * 64]; } g;        // 112 KB
        struct { bf16 q[4][64][72]; bf16 kst[64 * 256]; bf16 vst[64 * 256]; } e; // 100 KB
    } u;

    const int t    = threadIdx.x;
    const int lane = t & 63, wave = t >> 6;      // 12 waves
    const int wm   = wave & 3, ws = wave >> 2;   // row-quarter, section q/k/v
    const int orig = blockIdx.x;                 // 256 blocks, %8==0
    const int wg   = (orig & 7) * 32 + (orig >> 3);  // XCD-contiguous
    const int mt   = wg >> 3, h = wg & 7;
    const int m0   = mt * 256;

    const int l15 = lane & 15, l4 = lane >> 4;
    const int rl  = lane >> 3, cl = (lane & 7) ^ rl;   // swizzled GLD src chunk

    // ---- staging helpers ----
    auto issueA = [&](float4* areg, int k0) {    // fp32 x -> regs (issue only)
        #pragma unroll
        for (int j = 0; j < 6; ++j) {
            const int i = t + j * 768;
            if (i < 4096) {                      // wave-uniform guard (4096=5*768+256)
                const int row = i >> 4, ch = i & 15;
                areg[j] = *(const float4*)(x + (long)(m0 + row) * 512 + k0 + ch * 4);
            }
        }
    };
    auto writeA = [&](const float4* areg, int sl) {   // cvt + swizzled ds_write
        #pragma unroll
        for (int j = 0; j < 6; ++j) {
            const int i = t + j * 768;
            if (i < 4096) {
                const int row = i >> 4, ch = i & 15;
                float4 v = areg[j];
                bf16x4 o = { (bf16)v.x, (bf16)v.y, (bf16)v.z, (bf16)v.w };
                *(bf16x4*)(u.g.A[sl] + row * 64 + (((ch >> 1) ^ (row & 7)) * 8)
                           + (ch & 1) * 4) = o;
            }
        }
    };
    auto issueB = [&](int sl, int k0) {          // 24 chunks, 2 per wave
        #pragma unroll
        for (int i = 0; i < 2; ++i) {
            const int ch  = wave * 2 + i;        // 0..23
            const int sec = ch >> 3;             // 0=q 1=k 2=v
            const int r   = (ch & 7) * 8 + rl;   // row within section
            GLD16(Wt + ((sec * 512 + h * 64 + r) * 512 + k0 + cl * 8),
                  u.g.B[sl] + ch * 512);
        }
    };

    f32x4 acc[4][4] = {};
    auto compute = [&](int sl) {
        #pragma unroll
        for (int kh = 0; kh < 2; ++kh) {
            bf16x8 af[4], bfv[4];
            const int rc = kh * 4 + l4;
            #pragma unroll
            for (int mf = 0; mf < 4; ++mf) {
                const int row = wm * 64 + mf * 16 + l15;      // 0..255
                af[mf] = *(const bf16x8*)(u.g.A[sl] + row * 64 + ((rc ^ (row & 7)) * 8));
            }
            #pragma unroll
            for (int nf = 0; nf < 4; ++nf) {
                const int row = ws * 64 + nf * 16 + l15;      // 0..191
                bfv[nf] = *(const bf16x8*)(u.g.B[sl] + row * 64 + ((rc ^ (row & 7)) * 8));
            }
            #pragma unroll
            for (int mf = 0; mf < 4; ++mf)
                #pragma unroll
                for (int nf = 0; nf < 4; ++nf)
                    acc[mf][nf] = __builtin_amdgcn_mfma_f32_16x16x32_bf16(
                        af[mf], bfv[nf], acc[mf][nf], 0, 0, 0);
        }
    };

    // ---- prologue: stage 0 ----
    {
        float4 areg0[6];
        issueA(areg0, 0);
        issueB(0, 0);
        WAITVM(2);                               // A(0) regs arrived; B(0) flies
        __builtin_amdgcn_sched_barrier(0);
        writeA(areg0, 0);
        WAITLGKM0;
        __builtin_amdgcn_sched_barrier(0);
    }

    // ---- main loop: 8 K-steps ----
    #pragma unroll
    for (int st = 0; st < 8; ++st) {
        float4 areg[6];
        if (st < 7) {
            issueA(areg, (st + 1) * 64);         // A first (retires first)
            issueB((st + 1) & 1, (st + 1) * 64);
            if (wave < 4) { WAITVM(8); } else { WAITVM(7); }  // nA+nB
        } else {
            WAITVM(0);
        }
        __builtin_amdgcn_sched_barrier(0);
        __builtin_amdgcn_s_barrier();            // stage st complete for all
        compute(st & 1);
        if (st < 7) {
            WAITVM(2);                           // A(st+1) regs arrived
            __builtin_amdgcn_sched_barrier(0);
            writeA(areg, (st + 1) & 1);
        }
        WAITLGKM0;                               // ds_reads + ds_writes drained
        __builtin_amdgcn_sched_barrier(0);
        __builtin_amdgcn_s_barrier();            // safe to overwrite buf next
    }

    // ---------------- fused epilogue ----------------
    const int b  = m0 >> 11;
    const int bh = b * 8 + h;
    const int nwbase = (m0 & 2047) + wm * 64;    // seq offset of wave's 64 rows

    if (ws < 2) {
        // LayerNorm over d=64 (4 nf frags x 16 l15 lanes), stats from fp32 acc
        const float* gp = (ws == 0 ? gq : gk) + h * 64;
        const float* bp = (ws == 0 ? bq : bk) + h * 64;
        float gv[4], bv[4];
        #pragma unroll
        for (int nf = 0; nf < 4; ++nf) {
            gv[nf] = gp[nf * 16 + l15];
            bv[nf] = bp[nf * 16 + l15];
        }
        #pragma unroll
        for (int mf = 0; mf < 4; ++mf) {
            float mu[4], rs[4];
            #pragma unroll
            for (int r = 0; r < 4; ++r) {
                float s = 0.f, s2 = 0.f;
                #pragma unroll
                for (int nf = 0; nf < 4; ++nf) {
                    const float xv = acc[mf][nf][r];
                    s += xv; s2 += xv * xv;
                }
                s  += __shfl_xor(s, 1);  s  += __shfl_xor(s, 2);
                s  += __shfl_xor(s, 4);  s  += __shfl_xor(s, 8);
                s2 += __shfl_xor(s2, 1); s2 += __shfl_xor(s2, 2);
                s2 += __shfl_xor(s2, 4); s2 += __shfl_xor(s2, 8);
                mu[r] = s * (1.f / 64.f);
                rs[r] = rsqrtf(s2 * (1.f / 64.f) - mu[r] * mu[r] + 1e-5f);
            }
            #pragma unroll
            for (int nf = 0; nf < 4; ++nf) {
                bf16x4 pk;
                #pragma unroll
                for (int r = 0; r < 4; ++r)
                    pk[r] = (bf16)((acc[mf][nf][r] - mu[r]) * rs[r] * gv[nf] + bv[nf]);
                if (ws == 0) {
                    *(bf16x4*)(&u.e.q[wm][nf * 16 + l15][mf * 16 + l4 * 4]) = pk;
                } else {
                    const int d = nf * 16 + l15;
                    const int c = wm * 8 + mf * 2 + (l4 >> 1);   // 16B n-chunk 0..31
                    *(bf16x4*)(u.e.kst + d * 256 + ((c ^ ((d & 7) << 2)) * 8)
                               + (l4 & 1) * 4) = pk;
                }
            }
        }
    } else {
        // v: plain cast into vst[d'][256n], same swizzle
        #pragma unroll
        for (int mf = 0; mf < 4; ++mf)
            #pragma unroll
            for (int nf = 0; nf < 4; ++nf) {
                bf16x4 pk;
                #pragma unroll
                for (int r = 0; r < 4; ++r) pk[r] = (bf16)acc[mf][nf][r];
                const int d = nf * 16 + l15;
                const int c = wm * 8 + mf * 2 + (l4 >> 1);
                *(bf16x4*)(u.e.vst + d * 256 + ((c ^ ((d & 7) << 2)) * 8)
                           + (l4 & 1) * 4) = pk;
            }
    }

    if (ws == 0) {
        // wave-local 4x4 transpose q[d][n] -> qn[bh][n][d]
        bf16* dst = qn + ((long)bh * SEQ + nwbase) * 64;
        const int nq = lane & 15, dq2 = lane >> 4;
        #pragma unroll
        for (int j = 0; j < 4; ++j) {
            const int d0 = (j * 4 + dq2) * 4;
            bf16x4 a0 = *(const bf16x4*)(&u.e.q[wm][d0 + 0][nq * 4]);
            bf16x4 a1 = *(const bf16x4*)(&u.e.q[wm][d0 + 1][nq * 4]);
            bf16x4 a2 = *(const bf16x4*)(&u.e.q[wm][d0 + 2][nq * 4]);
            bf16x4 a3 = *(const bf16x4*)(&u.e.q[wm][d0 + 3][nq * 4]);
            #pragma unroll
            for (int c = 0; c < 4; ++c) {
                bf16x4 o = { a0[c], a1[c], a2[c], a3[c] };
                *(bf16x4*)(dst + (nq * 4 + c) * 64 + d0) = o;
            }
        }
    }

    __syncthreads();   // kst/vst complete for all waves; q-scratch reads done

    if (ws == 2) {
        // partial S[d'][d] over 256 rows; wave wm covers n-chunks wm*64..+63
        f32x4 sac[4][4] = {};
        #pragma unroll
        for (int kk = 0; kk < 2; ++kk) {
            const int c = (wm * 2 + kk) * 4 + l4;     // 16B chunk 0..31
            bf16x8 av[4], bk8[4];
            #pragma unroll
            for (int i = 0; i < 4; ++i) {
                const int dp = i * 16 + l15;
                av[i] = *(const bf16x8*)(u.e.vst + dp * 256 + ((c ^ ((dp & 7) << 2)) * 8));
            }
            #pragma unroll
            for (int j = 0; j < 4; ++j) {
                const int dd = j * 16 + l15;
                bk8[j] = *(const bf16x8*)(u.e.kst + dd * 256 + ((c ^ ((dd & 7) << 2)) * 8));
            }
            #pragma unroll
            for (int i = 0; i < 4; ++i)
                #pragma unroll
                for (int j = 0; j < 4; ++j)
                    sac[i][j] = __builtin_amdgcn_mfma_f32_16x16x32_bf16(
                        av[i], bk8[j], sac[i][j], 0, 0, 0);
        }
        // 4-way reduce across v-waves via LDS (aliases q area, free now)
        float* red = (float*)u.e.q;               // 2 x 16KB tiles
        float* r0  = red;
        float* r1  = red + 4096;
        if (wm < 2) {
            float* rd = (wm == 0) ? r0 : r1;
            #pragma unroll
            for (int i = 0; i < 4; ++i)
                #pragma unroll
                for (int j = 0; j < 4; ++j)
                    #pragma unroll
                    for (int r = 0; r < 4; ++r)
                        rd[(i * 16 + l4 * 4 + r) * 64 + j * 16 + l15] = sac[i][j][r];
        }
        WAITLGKM0;
        __builtin_amdgcn_s_barrier();
        if (wm >= 2) {
            float* rd = (wm == 2) ? r0 : r1;
            #pragma unroll
            for (int i = 0; i < 4; ++i)
                #pragma unroll
                for (int j = 0; j < 4; ++j)
                    #pragma unroll
                    for (int r = 0; r < 4; ++r)
                        rd[(i * 16 + l4 * 4 + r) * 64 + j * 16 + l15] += sac[i][j][r];
        }
        WAITLGKM0;
        __builtin_amdgcn_s_barrier();
        if (wm == 0) {
            float* Sb = Sp + (long)(mt * 8 + h) * 4096;
            #pragma unroll
            for (int i = 0; i < 4; ++i)
                #pragma unroll
                for (int j = 0; j < 4; ++j)
                    #pragma unroll
                    for (int r = 0; r < 4; ++r) {
                        const int idx = (i * 16 + l4 * 4 + r) * 64 + j * 16 + l15;
                        Sb[idx] = r0[idx] + r1[idx];
                    }
        }
    }
}

// ---------------------------------------------------------------------------
// Kernel 3 (tiny): reduce Sp (8 m-partials per bh) -> S[bh][64][64].
// ---------------------------------------------------------------------------
__global__ __launch_bounds__(256) void k_red(const float* __restrict__ Sp,
                                             float* __restrict__ S)
{
    const int bid = blockIdx.x;                  // 512 blocks
    const int bh = bid >> 4, chunk = bid & 15;
    const int b = bh >> 3, h = bh & 7;
    const int e = chunk * 256 + threadIdx.x;
    float s = 0.f;
    #pragma unroll
    for (int p = 0; p < 8; ++p)
        s += Sp[((long)((b * 8 + p) * 8 + h)) * 4096 + e];
    S[(long)bh * 4096 + e] = s;
}

// ---------------------------------------------------------------------------
// Kernel 4: out[b][n][h*64+d'] = sum_d qn[bh][n][d] * (S[bh][d'][d] * 2^-14)
// 512 blocks (32 bh x 16 n-tiles of 128), 4 waves x 32 rows.
// ---------------------------------------------------------------------------
__global__ __launch_bounds__(256) void k_out(const bf16* __restrict__ qn,
                                             const float* __restrict__ S,
                                             float* __restrict__ out)
{
    __shared__ float sS[64 * 68];                // padded [64][68]
    const int bid = blockIdx.x;
    const int bh = bid >> 4, nt16 = bid & 15;
    const int b = bh >> 3, h = bh & 7;
    const int t = threadIdx.x, lane = t & 63, wave = t >> 6;
    const int l15 = lane & 15, l4 = lane >> 4;

    #pragma unroll
    for (int j = 0; j < 4; ++j) {
        const int f  = j * 1024 + t * 4;
        const int dp = f >> 6, dd = f & 63;
        *(f32x4*)(sS + dp * 68 + dd) = *(const f32x4*)(S + (long)bh * 4096 + f);
    }
    __syncthreads();

    const float scale = 1.f / 16384.f;           // (64^-0.5)/2048 exactly
    bf16x8 bfr[2][4];
    #pragma unroll
    for (int kh = 0; kh < 2; ++kh)
        #pragma unroll
        for (int cf = 0; cf < 4; ++cf) {
            const float* p = sS + (cf * 16 + l15) * 68 + kh * 32 + l4 * 8;
            float4 lo = *(const float4*)(p);
            float4 hi = *(const float4*)(p + 4);
            bf16x8 f;
            f[0] = (bf16)(lo.x * scale); f[1] = (bf16)(lo.y * scale);
            f[2] = (bf16)(lo.z * scale); f[3] = (bf16)(lo.w * scale);
            f[4] = (bf16)(hi.x * scale); f[5] = (bf16)(hi.y * scale);
            f[6] = (bf16)(hi.z * scale); f[7] = (bf16)(hi.w * scale);
            bfr[kh][cf] = f;
        }

    const bf16* qb = qn + (long)bh * SEQ * 64;
    const int nbase = nt16 * 128 + wave * 32;

    #pragma unroll
    for (int mf = 0; mf < 2; ++mf) {
        bf16x8 a0 = *(const bf16x8*)(qb + (nbase + mf * 16 + l15) * 64 +      l4 * 8);
        bf16x8 a1 = *(const bf16x8*)(qb + (nbase + mf * 16 + l15) * 64 + 32 + l4 * 8);
        f32x4 acc[4] = {};
        #pragma unroll
        for (int cf = 0; cf < 4; ++cf) {
            acc[cf] = __builtin_amdgcn_mfma_f32_16x16x32_bf16(a0, bfr[0][cf], acc[cf], 0, 0, 0);
            acc[cf] = __builtin_amdgcn_mfma_f32_16x16x32_bf16(a1, bfr[1][cf], acc[cf], 0, 0, 0);
        }
        #pragma unroll
        for (int cf = 0; cf < 4; ++cf)
            #pragma unroll
            for (int r = 0; r < 4; ++r) {
                const int n = nbase + mf * 16 + l4 * 4 + r;
                out[((long)b * SEQ + n) * 512 + h * 64 + cf * 16 + l15] = acc[cf][r];
            }
    }
}

// ---------------------------------------------------------------------------
extern "C" void kernel_launch(void* const* d_in, const int* in_sizes, int n_in,
                              void* d_out, int out_size, void* d_ws, size_t ws_size,
                              hipStream_t stream)
{
    const float* x  = (const float*)d_in[0];
    const float* w  = (const float*)d_in[1];
    const float* gq = (const float*)d_in[2];
    const float* bq = (const float*)d_in[3];
    const float* gk = (const float*)d_in[4];
    const float* bk = (const float*)d_in[5];
    float* out = (float*)d_out;

    char* ws = (char*)d_ws;
    // layout (bytes):
    //   wt  bf16 : 0        .. 1572864
    //   qn  bf16 : 1572864  .. 9961472
    //   Sp  fp32 : 9961472  .. 14155776  (32 mt x 8 h x 4096 f32 = 4 MB)
    //   S   fp32 : 14155776 .. 14680064  (32 bh x 4096 f32)
    bf16*  wt = (bf16*)(ws);
    bf16*  qn = (bf16*)(ws + 1572864);
    float* Sp = (float*)(ws + 9961472);
    float* S  = (float*)(ws + 14155776);

    hipLaunchKernelGGL(k_prep, dim3(768), dim3(256), 0, stream, w, wt);
    hipLaunchKernelGGL(k_gemm, dim3(256), dim3(768), 0, stream,
                       x, wt, gq, bq, gk, bk, qn, Sp);
    hipLaunchKernelGGL(k_red,  dim3(512), dim3(256), 0, stream, Sp, S);
    hipLaunchKernelGGL(k_out,  dim3(512), dim3(256), 0, stream, qn, S, out);
}